// Round 11
// baseline (127.320 us; speedup 1.0000x reference)
//
#include <hip/hip_runtime.h>

// Fused SSIM loss via MFMA separable blur, horizontal-pass-first. B=32,
// C=1, 512x512, 11x11 separable gaussian. 4 fp16 planes: p,t,s=p^2+t^2,q=pt.
// Pass 1 (horizontal): A = raw rows (b128 from row-major LDS), B = band
//   g[k-n-3] (x-origin -8 => 16B-aligned float4 staging loads). D gives each
//   lane 4 consecutive y for one x -> packed f16x4 write into x-major vbufT.
// Pass 2 (vertical): A = band g[k-m], B = vbufT rows (b128). No transposes,
// no scalar LDS ops, float4 global staging. Rows 26..31 zero-filled so MFMA
// never sees uninitialized LDS (NaN x 0 = NaN).
// Reduction: plain per-block partial + tiny kernel (R8: atomics cost 200us).
typedef _Float16 f16x2 __attribute__((ext_vector_type(2)));
typedef _Float16 f16x4 __attribute__((ext_vector_type(4)));
typedef _Float16 f16x8 __attribute__((ext_vector_type(8)));
typedef float    f32x4 __attribute__((ext_vector_type(4)));

#define NBLK 8192    // 32 images * 8 x-tiles * 32 y-tiles

__device__ __forceinline__ f16x2 pkrtz(float a, float b) {
    return __builtin_bit_cast(f16x2, __builtin_amdgcn_cvt_pkrtz(a, b));
}
__device__ __forceinline__ f16x4 pack4(f32x4 v) {
    union { f16x2 h2[2]; f16x4 v4; } u;
    u.h2[0] = pkrtz(v[0], v[1]);
    u.h2[1] = pkrtz(v[2], v[3]);
    return u.v4;
}

__global__ __launch_bounds__(256, 3)
void ssim_fused(const float* __restrict__ pred,
                const float* __restrict__ targ,
                const float* __restrict__ win,
                float* __restrict__ partial)
{
    // raw:   [pl:4][ry:32][rx: stride 88] fp16 = 22528 B (80 rx used)
    // vbufT: [pl:4][x:64][vy: stride 40]  fp16 = 20480 B (32 vy used)
    __shared__ __align__(16) _Float16 raw[4 * 32 * 88];
    __shared__ __align__(16) _Float16 vbt[4 * 64 * 40];
    __shared__ float gw[16];
    __shared__ float wsum[4];

    const int tid  = threadIdx.x;
    const int lane = tid & 63;
    const int wv   = tid >> 6;
    const int bid  = blockIdx.x;
    const int b    = bid >> 8;        // 256 tiles per image
    const int rem  = bid & 255;
    const int ty   = rem >> 3;        // 0..31
    const int tx   = rem & 7;         // 0..7
    const int x0g  = tx * 64 - 8;     // raw rx=0 -> gx (16B-aligned chunks)
    const int y0g  = ty * 16 - 5;     // raw ry=0 -> gy

    // 1-D gaussian = row sums of the 2-D window (window sums to 1).
    if (tid < 11) {
        float s = 0.f;
        #pragma unroll
        for (int j = 0; j < 11; ++j) s += win[tid * 11 + j];
        gw[tid] = s;
    }

    const float* pb = pred + (size_t)b * (512 * 512);
    const float* tb = targ + (size_t)b * (512 * 512);
    const bool interior = (tx >= 1) & (tx <= 6) & (ty >= 1) & (ty <= 30);

    // ---- Stage 4 planes row-major, float4 loads, b64 LDS writes. ----
    // 640 positions = 32 rows x 20 float4-chunks; rows 26..31 forced zero.
    for (int ci = tid; ci < 640; ci += 256) {
        const int ry = ci / 20;
        const int rx = (ci % 20) << 2;
        const int gy = y0g + ry;
        const int gx = x0g + rx;
        f32x4 p4 = {0.f, 0.f, 0.f, 0.f};
        f32x4 t4 = {0.f, 0.f, 0.f, 0.f};
        if (ry < 26 && (interior ||
                        ((unsigned)gy < 512u && (unsigned)gx < 512u))) {
            const size_t off = (size_t)gy * 512 + gx;
            p4 = *(const f32x4*)(pb + off);
            t4 = *(const f32x4*)(tb + off);
        }
        f32x4 s4, q4;
        #pragma unroll
        for (int e = 0; e < 4; ++e) {
            s4[e] = fmaf(p4[e], p4[e], t4[e] * t4[e]);
            q4[e] = p4[e] * t4[e];
        }
        const int base = ry * 88 + rx;
        *(f16x4*)&raw[        base] = pack4(p4);
        *(f16x4*)&raw[2816  + base] = pack4(t4);
        *(f16x4*)&raw[5632  + base] = pack4(s4);
        *(f16x4*)&raw[8448  + base] = pack4(q4);
    }
    __syncthreads();

    // ---- Band fragments. Layouts (m89): A[m=lane&15][k=quad*8+j],
    // B[k=quad*8+j][n=lane&15], D col=lane&15 row=quad*4+r. ----
    const int mrow = lane & 15;
    const int quad = lane >> 4;
    f16x8 bh, av;    // pass-1 B-band g[k-n-3]; pass-2 A-band g[k-m]
    #pragma unroll
    for (int j = 0; j < 8; ++j) {
        const int kk = quad * 8 + j;
        const int dh = kk - mrow - 3;
        const int dv = kk - mrow;
        bh[j] = (dh >= 0 && dh < 11) ? (_Float16)gw[dh] : (_Float16)0.f;
        av[j] = (dv >= 0 && dv < 11) ? (_Float16)gw[dv] : (_Float16)0.f;
    }
    const f32x4 z4 = {0.f, 0.f, 0.f, 0.f};

    // ---- Pass 1 (horizontal): wave wv owns plane wv. 4 x-chunks x 2
    // y-halves. A = raw rows, lane m = y; D lane: x = X0+mrow fixed,
    // 4 consecutive y = quad*4+r -> one b64 write to x-major vbufT. ----
    #pragma unroll
    for (int wc = 0; wc < 4; ++wc) {
        #pragma unroll
        for (int h = 0; h < 2; ++h) {
            const f16x8 ar = *(const f16x8*)
                &raw[wv * 2816 + (h * 16 + mrow) * 88 + wc * 16 + quad * 8];
            const f32x4 d = __builtin_amdgcn_mfma_f32_16x16x32_f16(ar, bh, z4, 0, 0, 0);
            *(f16x4*)&vbt[wv * 2560 + (wc * 16 + mrow) * 40 + h * 16 + quad * 4]
                = pack4(d);
        }
    }
    __syncthreads();

    // ---- Pass 2 (vertical) + SSIM: wave wv owns x-chunk X0 = 16*wv. ----
    float lsum = 0.f;
    {
        const int X0 = wv << 4;
        f32x4 dq[4];
        #pragma unroll
        for (int pl = 0; pl < 4; ++pl) {
            const f16x8 bv = *(const f16x8*)
                &vbt[pl * 2560 + (X0 + mrow) * 40 + quad * 8];
            dq[pl] = __builtin_amdgcn_mfma_f32_16x16x32_f16(av, bv, z4, 0, 0, 0);
        }
        #pragma unroll
        for (int r = 0; r < 4; ++r) {
            const float mp = dq[0][r], mt = dq[1][r];
            const float sv = dq[2][r], qv = dq[3][r];
            const float mp2 = mp * mp, mt2 = mt * mt, mpt = mp * mt;
            const float sig = fmaxf(sv - mp2 - mt2, 0.f);
            const float cv  = qv - mpt;
            const float num = (2.f * mpt + 1e-4f) * (2.f * cv + 9e-4f);
            const float den = (mp2 + mt2 + 1e-4f) * (sig + 9e-4f);
            lsum += num * __builtin_amdgcn_rcpf(den + 1e-8f);
        }
    }

    // ---- Block reduce -> one plain float store per block. ----
    #pragma unroll
    for (int off = 32; off > 0; off >>= 1)
        lsum += __shfl_down(lsum, off, 64);
    if (lane == 0) wsum[wv] = lsum;
    __syncthreads();
    if (tid == 0)
        partial[bid] = wsum[0] + wsum[1] + wsum[2] + wsum[3];
}

__global__ __launch_bounds__(256)
void ssim_reduce(const float* __restrict__ partial, float* __restrict__ out)
{
    __shared__ double ws[4];
    double s = 0.0;
    const f32x4* p4 = (const f32x4*)partial;
    for (int i = threadIdx.x; i < NBLK / 4; i += 256) {
        const f32x4 v = p4[i];
        s += (double)v[0] + (double)v[1] + (double)v[2] + (double)v[3];
    }
    #pragma unroll
    for (int off = 32; off > 0; off >>= 1)
        s += __shfl_down(s, off, 64);
    if ((threadIdx.x & 63) == 0) ws[threadIdx.x >> 6] = s;
    __syncthreads();
    if (threadIdx.x == 0) {
        const double tot = ws[0] + ws[1] + ws[2] + ws[3];
        out[0] = (float)(1.0 - tot / 8388608.0);
    }
}

extern "C" void kernel_launch(void* const* d_in, const int* in_sizes, int n_in,
                              void* d_out, int out_size, void* d_ws, size_t ws_size,
                              hipStream_t stream)
{
    const float* pred = (const float*)d_in[0];
    const float* targ = (const float*)d_in[1];
    const float* win  = (const float*)d_in[2];
    float* out     = (float*)d_out;
    float* partial = (float*)d_ws;      // NBLK floats = 32 KiB scratch

    ssim_fused<<<NBLK, 256, 0, stream>>>(pred, targ, win, partial);
    ssim_reduce<<<1, 256, 0, stream>>>(partial, out);
}